// Round 4
// baseline (275.647 us; speedup 1.0000x reference)
//
#include <hip/hip_runtime.h>
#include <hip/hip_bf16.h>
#include <cstdint>

// Problem constants
#define DIMC  256
#define NH    8
#define HD    32
#define NPIX  2304       // 48*48
#define BATCH 2
#define KT    32
#define NWAVE 8          // waves per attn block
#define NTW   9          // k-tiles per wave (72 tiles / 8 waves)
#define KPW   288        // keys per wave (NTW*KT)

typedef short s16x8 __attribute__((ext_vector_type(8)));
typedef short s16x4 __attribute__((ext_vector_type(4)));
typedef float f32x4 __attribute__((ext_vector_type(4)));

#define MFMA32(A,B,C) __builtin_amdgcn_mfma_f32_16x16x32_bf16(A,B,C,0,0,0)

// RNA (round-to-nearest-away) bf16 helpers: 1 VALU each.
__device__ inline uint32_t rnau(float x) { return __float_as_uint(x) + 0x8000u; }
__device__ inline uint32_t pk2(uint32_t l_, uint32_t h_) {
  return __builtin_amdgcn_perm(h_, l_, 0x07060302u);  // lo short=l_, hi short=h_
}

// ---------------------------------------------------------------------------
// Pool: x_avg = (x + box3/9 + box5/25 + box7/49)/4, zero-pad, include_pad
// ---------------------------------------------------------------------------
__global__ __launch_bounds__(256) void pool_kernel(const float* __restrict__ x,
                                                   float* __restrict__ xavg) {
  const int plane = blockIdx.x;
  const float* xp = x + (size_t)plane * NPIX;
  __shared__ float sx[NPIX];
  __shared__ float h3[NPIX], h5[NPIX], h7[NPIX];
  const int t = threadIdx.x;
#pragma unroll
  for (int r = 0; r < 9; ++r) sx[r * 256 + t] = xp[r * 256 + t];
  __syncthreads();
#pragma unroll
  for (int r = 0; r < 9; ++r) {
    int p = r * 256 + t;
    int i = p / 48, j = p - i * 48;
    float a3 = 0.f, a5 = 0.f, a7 = 0.f;
#pragma unroll
    for (int dj = -3; dj <= 3; ++dj) {
      int jj = j + dj;
      if (jj < 0 || jj >= 48) continue;
      float v = sx[i * 48 + jj];
      a7 += v;
      if (dj >= -2 && dj <= 2) a5 += v;
      if (dj >= -1 && dj <= 1) a3 += v;
    }
    h3[p] = a3; h5[p] = a5; h7[p] = a7;
  }
  __syncthreads();
#pragma unroll
  for (int r = 0; r < 9; ++r) {
    int p = r * 256 + t;
    int i = p / 48, j = p - i * 48;
    float b3 = 0.f, b5 = 0.f, b7 = 0.f;
#pragma unroll
    for (int di = -3; di <= 3; ++di) {
      int ii = i + di;
      if (ii < 0 || ii >= 48) continue;
      int q = ii * 48 + j;
      b7 += h7[q];
      if (di >= -2 && di <= 2) b5 += h5[q];
      if (di >= -1 && di <= 1) b3 += h3[q];
    }
    xavg[(size_t)plane * NPIX + p] =
        0.25f * (sx[p] + b3 * (1.f / 9.f) + b5 * (1.f / 25.f) + b7 * (1.f / 49.f));
  }
}

// ---------------------------------------------------------------------------
// Fused converts: blocks 0..287 tconv(x), 288..575 tconv(xavg), 576..703 wconv
// All HI-ONLY. UNCHANGED.
// ---------------------------------------------------------------------------
__global__ __launch_bounds__(256) void conv_all(
    const float* __restrict__ x, const float* __restrict__ xavg,
    const float* __restrict__ qw, const float* __restrict__ kvw,
    const float* __restrict__ pw_,
    short* __restrict__ Xh, short* __restrict__ Ah,
    short* __restrict__ Wth) {
  const int bx = blockIdx.x;
  const int t = threadIdx.x;
  if (bx < 576) {
    const float* src = (bx < 288) ? x : xavg;
    short* dhi = (bx < 288) ? Xh : Ah;
    const int bb = (bx < 288) ? bx : bx - 288;
    const int n0 = (bb % 36) * 64, c0 = ((bb / 36) & 3) * 64, b = bb / 144;
    __shared__ __align__(16) float T[64][68];
    {
      const int c = t >> 2, n4 = (t & 3) * 16;
      const float* sp = src + ((size_t)b * DIMC + c0 + c) * NPIX + n0 + n4;
#pragma unroll
      for (int i2 = 0; i2 < 4; ++i2)
        *(f32x4*)&T[c][n4 + i2 * 4] = *(const f32x4*)(sp + i2 * 4);
    }
    __syncthreads();
    {
      const int n = t >> 2, c4 = (t & 3) * 16;
      float v[16];
#pragma unroll
      for (int i = 0; i < 16; ++i) v[i] = T[c4 + i][n];
      uint32_t a[16];
#pragma unroll
      for (int i = 0; i < 16; ++i) a[i] = rnau(v[i]);
      union { s16x8 s; uint32_t u[4]; } H0, H1;
#pragma unroll
      for (int j = 0; j < 4; ++j) {
        H0.u[j] = pk2(a[2 * j], a[2 * j + 1]);
        H1.u[j] = pk2(a[8 + 2 * j], a[8 + 2 * j + 1]);
      }
      const size_t off = ((size_t)b * NPIX + n0 + n) * DIMC + c0 + c4;
      *(s16x8*)(dhi + off) = H0.s; *(s16x8*)(dhi + off + 8) = H1.s;
    }
  } else {
    const int idx = ((bx - 576) * 256 + t) * 8;
    const float* s;
    int off;
    if (idx < 65536)       { s = qw;  off = idx; }
    else if (idx < 196608) { s = kvw; off = idx - 65536; }
    else                   { s = pw_; off = idx - 196608; }
    f32x4 x0 = *(const f32x4*)(s + off);
    f32x4 x1 = *(const f32x4*)(s + off + 4);
    float v[8] = {x0[0], x0[1], x0[2], x0[3], x1[0], x1[1], x1[2], x1[3]};
    uint32_t a[8];
#pragma unroll
    for (int i = 0; i < 8; ++i) a[i] = rnau(v[i]);
    union { s16x8 s; uint32_t u[4]; } H;
#pragma unroll
    for (int j = 0; j < 4; ++j) H.u[j] = pk2(a[2 * j], a[2 * j + 1]);
    *(s16x8*)(Wth + idx) = H.s;
  }
}

// ---------------------------------------------------------------------------
// QKV GEMM: single MFMA/tile (Wh*Xh). UNCHANGED.
// ---------------------------------------------------------------------------
__global__ __launch_bounds__(128) void gemm_qkv_hi(
    const short* __restrict__ Wth,
    const float* __restrict__ q_b, const float* __restrict__ kv_b,
    const short* __restrict__ Xh, const short* __restrict__ Ah,
    short* __restrict__ Qhi, short* __restrict__ Khi, short* __restrict__ Vhi,
    float qscale) {
  __shared__ __align__(16) float Cl[32][68];
  const int by = blockIdx.y;
  const bool isQ = (by < 8);
  const int o0 = isQ ? by * 32 : (by - 8) * 32;
  const short* Wh = isQ ? Wth : Wth + 65536;
  const float* bias = isQ ? q_b : kv_b;
  const short* Inh = isQ ? Xh : Ah;
  const float scale = isQ ? qscale : 1.0f;
  short* d1 = isQ ? Qhi : Khi;   // used when o0 < 256 (Q or K)
  const int n0 = blockIdx.x * 64;
  const int b  = blockIdx.z;

  const int tid = threadIdx.x;
  const int wave = tid >> 6, lane = tid & 63;
  const int g = lane >> 4, q = lane & 15;

  const short* wph = Wh + ((o0 + wave * 16 + q) * DIMC + g * 8);
  const short* iph = Inh + ((size_t)(b * NPIX + n0 + q) * DIMC + g * 8);

  f32x4 acc[4] = {{0,0,0,0},{0,0,0,0},{0,0,0,0},{0,0,0,0}};
#pragma unroll
  for (int c0 = 0; c0 < DIMC; c0 += 32) {
    s16x8 ah = *(const s16x8*)(wph + c0);
#pragma unroll
    for (int st = 0; st < 4; ++st) {
      s16x8 bh_ = *(const s16x8*)(iph + (size_t)st * 16 * DIMC + c0);
      acc[st] = MFMA32(ah, bh_, acc[st]);
    }
  }
#pragma unroll
  for (int st = 0; st < 4; ++st)
#pragma unroll
    for (int r = 0; r < 4; ++r)
      Cl[wave * 16 + g * 4 + r][st * 16 + q] = acc[st][r];
  __syncthreads();

  if (o0 < 256) {
    // Q or K: (C+bias)*scale, hi-only, layout [bh][n][32]
    const int n = tid >> 1, oq = tid & 1;
    const int h = o0 >> 5;
    const float* bp = bias + o0 + oq * 16;
    float v[16];
#pragma unroll
    for (int i = 0; i < 16; ++i) v[i] = (Cl[oq * 16 + i][n] + bp[i]) * scale;
    uint32_t a[16];
#pragma unroll
    for (int i = 0; i < 16; ++i) a[i] = rnau(v[i]);
    union { s16x8 s; uint32_t u[4]; } H0, H1;
#pragma unroll
    for (int j = 0; j < 4; ++j) {
      H0.u[j] = pk2(a[2 * j], a[2 * j + 1]);
      H1.u[j] = pk2(a[8 + 2 * j], a[8 + 2 * j + 1]);
    }
    const size_t off = ((size_t)((b * 8 + h) * NPIX + n0 + n)) * HD + oq * 16;
    *(s16x8*)(d1 + off) = H0.s; *(s16x8*)(d1 + off + 8) = H1.s;
  } else {
    // V hi-only: dst [bh][d][n]
    const int o = tid >> 2, nc = (tid & 3) * 16;
    const int h = (o0 - 256) >> 5;
    const float bv = bias[o0 + o];
    float v[16];
#pragma unroll
    for (int i2 = 0; i2 < 4; ++i2) {
      f32x4 t4 = *(const f32x4*)&Cl[o][nc + i2 * 4];
      v[i2 * 4 + 0] = t4[0] + bv; v[i2 * 4 + 1] = t4[1] + bv;
      v[i2 * 4 + 2] = t4[2] + bv; v[i2 * 4 + 3] = t4[3] + bv;
    }
    uint32_t a[16];
#pragma unroll
    for (int i = 0; i < 16; ++i) a[i] = rnau(v[i]);
    union { s16x8 s; uint32_t u[4]; } H0, H1;
#pragma unroll
    for (int j = 0; j < 4; ++j) {
      H0.u[j] = pk2(a[2 * j], a[2 * j + 1]);
      H1.u[j] = pk2(a[8 + 2 * j], a[8 + 2 * j + 1]);
    }
    const size_t off = ((size_t)((b * 8 + h) * HD + o)) * NPIX + n0 + nc;
    *(s16x8*)(Vhi + off) = H0.s; *(s16x8*)(Vhi + off + 8) = H1.s;
  }
}

// ---------------------------------------------------------------------------
// MFMA flash attention, 8-way INTRA-BLOCK split-K + XCD-aware swizzle:
//   block = 8 waves over the SAME 32 q-rows; wave w owns k-tiles
//   [w*9, w*9+9) (288 keys). Partial O (f32) + L reduced across waves via
//   LDS (aliased over the P-staging buffer), normalized, written directly
//   in the torch-scramble layout z[b][(n%9)*256 + h*32 + d][n/9].
// Swizzle: bh = 2*(li&7) + (li>>3)/72 puts each bh-pair's 144 blocks on ONE
//   XCD (round-robin li%8) -> K/V footprint 576KB per L2 (was 4.6MB thrash).
// ---------------------------------------------------------------------------
__global__ __launch_bounds__(512, 6) void attn_fused(
    const short* __restrict__ Qhi,   // [bh][n][32]
    const short* __restrict__ Khi,   // [bh][n][32]
    const short* __restrict__ Vhi,   // [bh][32][N]
    short* __restrict__ zh) {        // [b][pix][256] scrambled
  const int li = blockIdx.x;         // 0..1151
  const int r144 = li >> 3;          // 0..143
  const int bh = 2 * (li & 7) + (r144 >= 72 ? 1 : 0);
  const int qb = (r144 >= 72) ? r144 - 72 : r144;  // 32-row q block
  const int tid = threadIdx.x;
  const int wave = tid >> 6, lane = tid & 63;
  const int g = lane >> 4, q = lane & 15;
  const int base = qb * 32;

  // smem: phase 1 = P staging [8 waves][2 bufs][16*40 shorts] (20480 B)
  //       phase 2 = reduction  [8 waves][64 lanes][20 f32]    (40960 B)
  __shared__ __align__(16) float smemf[8 * 64 * 20];
  short* pwA = (short*)smemf + wave * 1280;
  short* pwB = pwA + 640;
  float (*R)[64][20] = (float (*)[64][20])smemf;

  const size_t qoff = ((size_t)bh * NPIX + base + q) * HD + g * 8;
  const s16x8 qhA = *(const s16x8*)(Qhi + qoff);
  const s16x8 qhB = *(const s16x8*)(Qhi + qoff + 16 * HD);

  const short* kp = Khi + ((size_t)bh * NPIX + wave * KPW + q) * HD + g * 8;
  const short* vp = Vhi + ((size_t)bh * HD + q) * NPIX + wave * KPW + g * 8;

  const f32x4 Z4 = {0.f, 0.f, 0.f, 0.f};
  f32x4 OA0 = Z4, OA1 = Z4, OB0 = Z4, OB1 = Z4;
  f32x4 LA = Z4, LB = Z4;
  s16x8 kb[3][2], vb[3][2], pfA, pfB, vp0, vp1;

  union { s16x8 s; uint32_t u[4]; } ONE, ZZ;
  ONE.u[0] = 0x3F803F80u; ONE.u[1] = 0x3F803F80u;
  ONE.u[2] = 0x3F803F80u; ONE.u[3] = 0x3F803F80u;
  ZZ.u[0] = 0; ZZ.u[1] = 0; ZZ.u[2] = 0; ZZ.u[3] = 0;
  const s16x8 ones = ONE.s;
  pfA = ZZ.s; pfB = ZZ.s;          // P=0 -> first O/L MFMAs add exact 0
  vp0 = ones; vp1 = ones;          // finite (avoid NaN*0)

  kb[0][0] = *(const s16x8*)(kp);
  kb[0][1] = *(const s16x8*)(kp + 16 * HD);
  vb[0][0] = *(const s16x8*)(vp);
  vb[0][1] = *(const s16x8*)(vp + 16 * NPIX);
  kb[1][0] = *(const s16x8*)(kp + KT * HD);
  kb[1][1] = *(const s16x8*)(kp + KT * HD + 16 * HD);
  vb[1][0] = *(const s16x8*)(vp + KT);
  vb[1][1] = *(const s16x8*)(vp + KT + 16 * NPIX);

#define ATTN_STEP(CUR, NX2, T)                                                \
  {                                                                           \
    if ((T) + 2 < NTW) {                                                      \
      const short* kpn = kp + ((T) + 2) * (KT * HD);                          \
      const short* vpn = vp + ((T) + 2) * KT;                                 \
      kb[NX2][0] = *(const s16x8*)(kpn);                                      \
      kb[NX2][1] = *(const s16x8*)(kpn + 16 * HD);                            \
      vb[NX2][0] = *(const s16x8*)(vpn);                                      \
      vb[NX2][1] = *(const s16x8*)(vpn + 16 * NPIX);                          \
    }                                                                         \
    f32x4 SA0 = MFMA32(kb[CUR][0], qhA, Z4);                                  \
    f32x4 SA1 = MFMA32(kb[CUR][1], qhA, Z4);                                  \
    f32x4 SB0 = MFMA32(kb[CUR][0], qhB, Z4);                                  \
    f32x4 SB1 = MFMA32(kb[CUR][1], qhB, Z4);                                  \
    OA0 = MFMA32(vp0, pfA, OA0);                                              \
    OA1 = MFMA32(vp1, pfA, OA1);                                              \
    OB0 = MFMA32(vp0, pfB, OB0);                                              \
    OB1 = MFMA32(vp1, pfB, OB1);                                              \
    LA  = MFMA32(ones, pfA, LA);                                              \
    LB  = MFMA32(ones, pfB, LB);                                              \
    {                                                                         \
      f32x4 p0, p1;                                                           \
      p0[0] = exp2f(SA0[0]); p0[1] = exp2f(SA0[1]);                           \
      p0[2] = exp2f(SA0[2]); p0[3] = exp2f(SA0[3]);                           \
      p1[0] = exp2f(SA1[0]); p1[1] = exp2f(SA1[1]);                           \
      p1[2] = exp2f(SA1[2]); p1[3] = exp2f(SA1[3]);                           \
      uint2 w0, w1;                                                           \
      w0.x = pk2(rnau(p0[0]), rnau(p0[1])); w0.y = pk2(rnau(p0[2]), rnau(p0[3])); \
      w1.x = pk2(rnau(p1[0]), rnau(p1[1])); w1.y = pk2(rnau(p1[2]), rnau(p1[3])); \
      *(uint2*)&pwA[q * 40 + g * 4] = w0;                                     \
      *(uint2*)&pwA[q * 40 + 16 + g * 4] = w1;                                \
    }                                                                         \
    {                                                                         \
      f32x4 p0, p1;                                                           \
      p0[0] = exp2f(SB0[0]); p0[1] = exp2f(SB0[1]);                           \
      p0[2] = exp2f(SB0[2]); p0[3] = exp2f(SB0[3]);                           \
      p1[0] = exp2f(SB1[0]); p1[1] = exp2f(SB1[1]);                           \
      p1[2] = exp2f(SB1[2]); p1[3] = exp2f(SB1[3]);                           \
      uint2 w0, w1;                                                           \
      w0.x = pk2(rnau(p0[0]), rnau(p0[1])); w0.y = pk2(rnau(p0[2]), rnau(p0[3])); \
      w1.x = pk2(rnau(p1[0]), rnau(p1[1])); w1.y = pk2(rnau(p1[2]), rnau(p1[3])); \
      *(uint2*)&pwB[q * 40 + g * 4] = w0;                                     \
      *(uint2*)&pwB[q * 40 + 16 + g * 4] = w1;                                \
    }                                                                         \
    vp0 = vb[CUR][0]; vp1 = vb[CUR][1];                                       \
    pfA = *(const s16x8*)&pwA[q * 40 + g * 8];                                \
    pfB = *(const s16x8*)&pwB[q * 40 + g * 8];                                \
  }

#pragma unroll 1
  for (int tt = 0; tt < NTW; tt += 3) {
    ATTN_STEP(0, 2, tt);
    ATTN_STEP(1, 0, tt + 1);
    ATTN_STEP(2, 1, tt + 2);
  }
#undef ATTN_STEP

  // Tail: consume P of the wave's last tile
  OA0 = MFMA32(vp0, pfA, OA0);
  OA1 = MFMA32(vp1, pfA, OA1);
  OB0 = MFMA32(vp0, pfB, OB0);
  OB1 = MFMA32(vp1, pfB, OB1);
  LA  = MFMA32(ones, pfA, LA);
  LB  = MFMA32(ones, pfB, LB);

  // All waves done with P staging -> safe to alias as reduction buffer.
  __syncthreads();
  {
    float* rw = &R[wave][lane][0];
    *(f32x4*)&rw[0]  = OA0;   // d = g*4+r        (rows nA)
    *(f32x4*)&rw[4]  = OA1;   // d = 16+g*4+r
    *(f32x4*)&rw[8]  = OB0;   // d = g*4+r        (rows nB)
    *(f32x4*)&rw[12] = OB1;   // d = 16+g*4+r
    rw[16] = LA[0];           // L rows identical -> LA[0] = L[q-row A]
    rw[17] = LB[0];
  }
  __syncthreads();
  {
    // 512 threads: lane-slot l2 (same (g2,q2) mapping), eg in 0..7 picks
    // 2 O-elements: eg<4 -> A-half, else B-half; idx=(eg&3)*2 in the half.
    const int l2 = tid & 63, eg = tid >> 6;
    const int g2 = l2 >> 4, q2 = l2 & 15;
    const int isB = eg >> 2;
    const int idx = (eg & 3) * 2;
    float s0 = 0.f, s1 = 0.f, Lt = 0.f;
#pragma unroll
    for (int w = 0; w < NWAVE; ++w) {
      const float* rw = &R[w][l2][0];
      s0 += rw[isB * 8 + idx];
      s1 += rw[isB * 8 + idx + 1];
      Lt += rw[16 + isB];
    }
    const float inv = 1.f / Lt;
    const int h = bh & 7, b = bh >> 3;
    const int n = base + isB * 16 + q2;
    const int d0 = (idx < 4) ? (g2 * 4 + idx) : (16 + g2 * 4 + (idx - 4));
    const int c = n / 9, r = n - c * 9;
    short* zp = zh + ((size_t)(b * NPIX + r * 256 + h * HD + d0)) * DIMC + c;
    zp[0]    = (short)(rnau(s0 * inv) >> 16);
    zp[DIMC] = (short)(rnau(s1 * inv) >> 16);
  }
}

// ---------------------------------------------------------------------------
// PROJ GEMM: single MFMA/tile (Wh*Zh). fp32 out + bias. UNCHANGED.
// ---------------------------------------------------------------------------
__global__ __launch_bounds__(128) void gemm_proj_hi(
    const short* __restrict__ Wh,
    const float* __restrict__ bias,
    const short* __restrict__ Zh,
    float* __restrict__ out) {
  __shared__ __align__(16) float Cl[32][68];
  const int n0 = blockIdx.x * 64;
  const int o0 = blockIdx.y * 32;
  const int b  = blockIdx.z;
  const int tid = threadIdx.x;
  const int wave = tid >> 6, lane = tid & 63;
  const int g = lane >> 4, q = lane & 15;

  const short* wph = Wh + ((o0 + wave * 16 + q) * DIMC + g * 8);
  const short* iph = Zh + ((size_t)(b * NPIX + n0 + q) * DIMC + g * 8);

  f32x4 acc[4] = {{0,0,0,0},{0,0,0,0},{0,0,0,0},{0,0,0,0}};
#pragma unroll
  for (int c0 = 0; c0 < DIMC; c0 += 32) {
    s16x8 ah = *(const s16x8*)(wph + c0);
#pragma unroll
    for (int st = 0; st < 4; ++st) {
      s16x8 bh_ = *(const s16x8*)(iph + (size_t)st * 16 * DIMC + c0);
      acc[st] = MFMA32(ah, bh_, acc[st]);
    }
  }
#pragma unroll
  for (int st = 0; st < 4; ++st)
#pragma unroll
    for (int r = 0; r < 4; ++r)
      Cl[wave * 16 + g * 4 + r][st * 16 + q] = acc[st][r];
  __syncthreads();

  const int o = tid >> 2, nc = (tid & 3) * 16;
  const float bv = bias[o0 + o];
  float* op = out + ((size_t)b * DIMC + o0 + o) * NPIX + n0 + nc;
#pragma unroll
  for (int i2 = 0; i2 < 4; ++i2) {
    f32x4 v = *(const f32x4*)&Cl[o][nc + i2 * 4];
    v[0] += bv; v[1] += bv; v[2] += bv; v[3] += bv;
    *(f32x4*)(op + i2 * 4) = v;
  }
}

// ---------------------------------------------------------------------------
extern "C" void kernel_launch(void* const* d_in, const int* in_sizes, int n_in,
                              void* d_out, int out_size, void* d_ws, size_t ws_size,
                              hipStream_t stream) {
  const float* x      = (const float*)d_in[0];
  const float* q_w    = (const float*)d_in[1];
  const float* q_b    = (const float*)d_in[2];
  const float* kv_w   = (const float*)d_in[3];
  const float* kv_b   = (const float*)d_in[4];
  const float* proj_w = (const float*)d_in[5];
  const float* proj_b = (const float*)d_in[6];
  float* out = (float*)d_out;

  // Workspace (offsets preserved).
  char* w = (char*)d_ws;
  float* xavg = (float*)w;                       // 4,718,592
  short* Xh   = (short*)(w + 4718592);
  short* Ah   = (short*)(w + 9437184);
  short* Wth  = (short*)(w + 28311552);          // 524,288 (hi only)
  short* Qhi  = (short*)(w + 29360128);          // 2,359,296
  short* Khi  = (short*)(w + 31719424);
  short* Vhi  = (short*)(w + 34078720);
  short* Zh   = (short*)(w + 37322752);          // 2,359,296

  const float qscale = 0.17677669529663689f * 1.4426950408889634f; // d^-0.5*log2(e)

  pool_kernel<<<BATCH * DIMC, 256, 0, stream>>>(x, xavg);
  conv_all<<<704, 256, 0, stream>>>(x, xavg, q_w, kv_w, proj_w, Xh, Ah, Wth);
  gemm_qkv_hi<<<dim3(36, 24, 2), 128, 0, stream>>>(Wth, q_b, kv_b,
                                                   Xh, Ah, Qhi, Khi, Vhi, qscale);
  attn_fused<<<1152, 512, 0, stream>>>(Qhi, Khi, Vhi, Zh);
  gemm_proj_hi<<<dim3(36, 8, 2), 128, 0, stream>>>(Wth + 196608, proj_b, Zh, out);
}

// Round 5
// 156.408 us; speedup vs baseline: 1.7624x; 1.7624x over previous
//
#include <hip/hip_runtime.h>
#include <hip/hip_bf16.h>
#include <cstdint>

// Problem constants
#define DIMC  256
#define NH    8
#define HD    32
#define NPIX  2304       // 48*48
#define BATCH 2
#define KT    32
#define NWAVE 8          // waves per attn block
#define NTW   9          // k-tiles per wave (72 tiles / 8 waves)
#define KPW   288        // keys per wave (NTW*KT)

typedef short s16x8 __attribute__((ext_vector_type(8)));
typedef short s16x4 __attribute__((ext_vector_type(4)));
typedef float f32x4 __attribute__((ext_vector_type(4)));

#define MFMA32(A,B,C) __builtin_amdgcn_mfma_f32_16x16x32_bf16(A,B,C,0,0,0)

// RNA (round-to-nearest-away) bf16 helpers: 1 VALU each.
__device__ inline uint32_t rnau(float x) { return __float_as_uint(x) + 0x8000u; }
__device__ inline uint32_t pk2(uint32_t l_, uint32_t h_) {
  return __builtin_amdgcn_perm(h_, l_, 0x07060302u);  // lo short=l_, hi short=h_
}

// ---------------------------------------------------------------------------
// Pool: x_avg = (x + box3/9 + box5/25 + box7/49)/4, zero-pad, include_pad
// ---------------------------------------------------------------------------
__global__ __launch_bounds__(256) void pool_kernel(const float* __restrict__ x,
                                                   float* __restrict__ xavg) {
  const int plane = blockIdx.x;
  const float* xp = x + (size_t)plane * NPIX;
  __shared__ float sx[NPIX];
  __shared__ float h3[NPIX], h5[NPIX], h7[NPIX];
  const int t = threadIdx.x;
#pragma unroll
  for (int r = 0; r < 9; ++r) sx[r * 256 + t] = xp[r * 256 + t];
  __syncthreads();
#pragma unroll
  for (int r = 0; r < 9; ++r) {
    int p = r * 256 + t;
    int i = p / 48, j = p - i * 48;
    float a3 = 0.f, a5 = 0.f, a7 = 0.f;
#pragma unroll
    for (int dj = -3; dj <= 3; ++dj) {
      int jj = j + dj;
      if (jj < 0 || jj >= 48) continue;
      float v = sx[i * 48 + jj];
      a7 += v;
      if (dj >= -2 && dj <= 2) a5 += v;
      if (dj >= -1 && dj <= 1) a3 += v;
    }
    h3[p] = a3; h5[p] = a5; h7[p] = a7;
  }
  __syncthreads();
#pragma unroll
  for (int r = 0; r < 9; ++r) {
    int p = r * 256 + t;
    int i = p / 48, j = p - i * 48;
    float b3 = 0.f, b5 = 0.f, b7 = 0.f;
#pragma unroll
    for (int di = -3; di <= 3; ++di) {
      int ii = i + di;
      if (ii < 0 || ii >= 48) continue;
      int q = ii * 48 + j;
      b7 += h7[q];
      if (di >= -2 && di <= 2) b5 += h5[q];
      if (di >= -1 && di <= 1) b3 += h3[q];
    }
    xavg[(size_t)plane * NPIX + p] =
        0.25f * (sx[p] + b3 * (1.f / 9.f) + b5 * (1.f / 25.f) + b7 * (1.f / 49.f));
  }
}

// ---------------------------------------------------------------------------
// Fused converts: blocks 0..287 tconv(x), 288..575 tconv(xavg), 576..703 wconv
// All HI-ONLY. UNCHANGED.
// ---------------------------------------------------------------------------
__global__ __launch_bounds__(256) void conv_all(
    const float* __restrict__ x, const float* __restrict__ xavg,
    const float* __restrict__ qw, const float* __restrict__ kvw,
    const float* __restrict__ pw_,
    short* __restrict__ Xh, short* __restrict__ Ah,
    short* __restrict__ Wth) {
  const int bx = blockIdx.x;
  const int t = threadIdx.x;
  if (bx < 576) {
    const float* src = (bx < 288) ? x : xavg;
    short* dhi = (bx < 288) ? Xh : Ah;
    const int bb = (bx < 288) ? bx : bx - 288;
    const int n0 = (bb % 36) * 64, c0 = ((bb / 36) & 3) * 64, b = bb / 144;
    __shared__ __align__(16) float T[64][68];
    {
      const int c = t >> 2, n4 = (t & 3) * 16;
      const float* sp = src + ((size_t)b * DIMC + c0 + c) * NPIX + n0 + n4;
#pragma unroll
      for (int i2 = 0; i2 < 4; ++i2)
        *(f32x4*)&T[c][n4 + i2 * 4] = *(const f32x4*)(sp + i2 * 4);
    }
    __syncthreads();
    {
      const int n = t >> 2, c4 = (t & 3) * 16;
      float v[16];
#pragma unroll
      for (int i = 0; i < 16; ++i) v[i] = T[c4 + i][n];
      uint32_t a[16];
#pragma unroll
      for (int i = 0; i < 16; ++i) a[i] = rnau(v[i]);
      union { s16x8 s; uint32_t u[4]; } H0, H1;
#pragma unroll
      for (int j = 0; j < 4; ++j) {
        H0.u[j] = pk2(a[2 * j], a[2 * j + 1]);
        H1.u[j] = pk2(a[8 + 2 * j], a[8 + 2 * j + 1]);
      }
      const size_t off = ((size_t)b * NPIX + n0 + n) * DIMC + c0 + c4;
      *(s16x8*)(dhi + off) = H0.s; *(s16x8*)(dhi + off + 8) = H1.s;
    }
  } else {
    const int idx = ((bx - 576) * 256 + t) * 8;
    const float* s;
    int off;
    if (idx < 65536)       { s = qw;  off = idx; }
    else if (idx < 196608) { s = kvw; off = idx - 65536; }
    else                   { s = pw_; off = idx - 196608; }
    f32x4 x0 = *(const f32x4*)(s + off);
    f32x4 x1 = *(const f32x4*)(s + off + 4);
    float v[8] = {x0[0], x0[1], x0[2], x0[3], x1[0], x1[1], x1[2], x1[3]};
    uint32_t a[8];
#pragma unroll
    for (int i = 0; i < 8; ++i) a[i] = rnau(v[i]);
    union { s16x8 s; uint32_t u[4]; } H;
#pragma unroll
    for (int j = 0; j < 4; ++j) H.u[j] = pk2(a[2 * j], a[2 * j + 1]);
    *(s16x8*)(Wth + idx) = H.s;
  }
}

// ---------------------------------------------------------------------------
// QKV GEMM: single MFMA/tile (Wh*Xh). UNCHANGED.
// ---------------------------------------------------------------------------
__global__ __launch_bounds__(128) void gemm_qkv_hi(
    const short* __restrict__ Wth,
    const float* __restrict__ q_b, const float* __restrict__ kv_b,
    const short* __restrict__ Xh, const short* __restrict__ Ah,
    short* __restrict__ Qhi, short* __restrict__ Khi, short* __restrict__ Vhi,
    float qscale) {
  __shared__ __align__(16) float Cl[32][68];
  const int by = blockIdx.y;
  const bool isQ = (by < 8);
  const int o0 = isQ ? by * 32 : (by - 8) * 32;
  const short* Wh = isQ ? Wth : Wth + 65536;
  const float* bias = isQ ? q_b : kv_b;
  const short* Inh = isQ ? Xh : Ah;
  const float scale = isQ ? qscale : 1.0f;
  short* d1 = isQ ? Qhi : Khi;   // used when o0 < 256 (Q or K)
  const int n0 = blockIdx.x * 64;
  const int b  = blockIdx.z;

  const int tid = threadIdx.x;
  const int wave = tid >> 6, lane = tid & 63;
  const int g = lane >> 4, q = lane & 15;

  const short* wph = Wh + ((o0 + wave * 16 + q) * DIMC + g * 8);
  const short* iph = Inh + ((size_t)(b * NPIX + n0 + q) * DIMC + g * 8);

  f32x4 acc[4] = {{0,0,0,0},{0,0,0,0},{0,0,0,0},{0,0,0,0}};
#pragma unroll
  for (int c0 = 0; c0 < DIMC; c0 += 32) {
    s16x8 ah = *(const s16x8*)(wph + c0);
#pragma unroll
    for (int st = 0; st < 4; ++st) {
      s16x8 bh_ = *(const s16x8*)(iph + (size_t)st * 16 * DIMC + c0);
      acc[st] = MFMA32(ah, bh_, acc[st]);
    }
  }
#pragma unroll
  for (int st = 0; st < 4; ++st)
#pragma unroll
    for (int r = 0; r < 4; ++r)
      Cl[wave * 16 + g * 4 + r][st * 16 + q] = acc[st][r];
  __syncthreads();

  if (o0 < 256) {
    // Q or K: (C+bias)*scale, hi-only, layout [bh][n][32]
    const int n = tid >> 1, oq = tid & 1;
    const int h = o0 >> 5;
    const float* bp = bias + o0 + oq * 16;
    float v[16];
#pragma unroll
    for (int i = 0; i < 16; ++i) v[i] = (Cl[oq * 16 + i][n] + bp[i]) * scale;
    uint32_t a[16];
#pragma unroll
    for (int i = 0; i < 16; ++i) a[i] = rnau(v[i]);
    union { s16x8 s; uint32_t u[4]; } H0, H1;
#pragma unroll
    for (int j = 0; j < 4; ++j) {
      H0.u[j] = pk2(a[2 * j], a[2 * j + 1]);
      H1.u[j] = pk2(a[8 + 2 * j], a[8 + 2 * j + 1]);
    }
    const size_t off = ((size_t)((b * 8 + h) * NPIX + n0 + n)) * HD + oq * 16;
    *(s16x8*)(d1 + off) = H0.s; *(s16x8*)(d1 + off + 8) = H1.s;
  } else {
    // V hi-only: dst [bh][d][n]
    const int o = tid >> 2, nc = (tid & 3) * 16;
    const int h = (o0 - 256) >> 5;
    const float bv = bias[o0 + o];
    float v[16];
#pragma unroll
    for (int i2 = 0; i2 < 4; ++i2) {
      f32x4 t4 = *(const f32x4*)&Cl[o][nc + i2 * 4];
      v[i2 * 4 + 0] = t4[0] + bv; v[i2 * 4 + 1] = t4[1] + bv;
      v[i2 * 4 + 2] = t4[2] + bv; v[i2 * 4 + 3] = t4[3] + bv;
    }
    uint32_t a[16];
#pragma unroll
    for (int i = 0; i < 16; ++i) a[i] = rnau(v[i]);
    union { s16x8 s; uint32_t u[4]; } H0, H1;
#pragma unroll
    for (int j = 0; j < 4; ++j) {
      H0.u[j] = pk2(a[2 * j], a[2 * j + 1]);
      H1.u[j] = pk2(a[8 + 2 * j], a[8 + 2 * j + 1]);
    }
    const size_t off = ((size_t)((b * 8 + h) * HD + o)) * NPIX + n0 + nc;
    *(s16x8*)(Vhi + off) = H0.s; *(s16x8*)(Vhi + off + 8) = H1.s;
  }
}

// ---------------------------------------------------------------------------
// MFMA flash attention, 8-way INTRA-BLOCK split-K + XCD-aware swizzle.
// R3 structure, but launch_bounds WITHOUT a min-waves clamp: R3's
// __launch_bounds__(512,6) capped VGPR at 40 and spilled ~70 regs/thread
// to scratch (FETCH 240MB, WRITE 449MB). Registers > occupancy here.
// ---------------------------------------------------------------------------
__global__ __launch_bounds__(512) void attn_fused(
    const short* __restrict__ Qhi,   // [bh][n][32]
    const short* __restrict__ Khi,   // [bh][n][32]
    const short* __restrict__ Vhi,   // [bh][32][N]
    short* __restrict__ zh) {        // [b][pix][256] scrambled
  const int li = blockIdx.x;         // 0..1151
  const int r144 = li >> 3;          // 0..143
  const int bh = 2 * (li & 7) + (r144 >= 72 ? 1 : 0);
  const int qb = (r144 >= 72) ? r144 - 72 : r144;  // 32-row q block
  const int tid = threadIdx.x;
  const int wave = tid >> 6, lane = tid & 63;
  const int g = lane >> 4, q = lane & 15;
  const int base = qb * 32;

  // smem: phase 1 = P staging [8 waves][2 bufs][16*40 shorts] (20480 B)
  //       phase 2 = reduction  [8 waves][64 lanes][20 f32]    (40960 B)
  __shared__ __align__(16) float smemf[8 * 64 * 20];
  short* pwA = (short*)smemf + wave * 1280;
  short* pwB = pwA + 640;
  float (*R)[64][20] = (float (*)[64][20])smemf;

  const size_t qoff = ((size_t)bh * NPIX + base + q) * HD + g * 8;
  const s16x8 qhA = *(const s16x8*)(Qhi + qoff);
  const s16x8 qhB = *(const s16x8*)(Qhi + qoff + 16 * HD);

  const short* kp = Khi + ((size_t)bh * NPIX + wave * KPW + q) * HD + g * 8;
  const short* vp = Vhi + ((size_t)bh * HD + q) * NPIX + wave * KPW + g * 8;

  const f32x4 Z4 = {0.f, 0.f, 0.f, 0.f};
  f32x4 OA0 = Z4, OA1 = Z4, OB0 = Z4, OB1 = Z4;
  f32x4 LA = Z4, LB = Z4;
  s16x8 kb[3][2], vb[3][2], pfA, pfB, vp0, vp1;

  union { s16x8 s; uint32_t u[4]; } ONE, ZZ;
  ONE.u[0] = 0x3F803F80u; ONE.u[1] = 0x3F803F80u;
  ONE.u[2] = 0x3F803F80u; ONE.u[3] = 0x3F803F80u;
  ZZ.u[0] = 0; ZZ.u[1] = 0; ZZ.u[2] = 0; ZZ.u[3] = 0;
  const s16x8 ones = ONE.s;
  pfA = ZZ.s; pfB = ZZ.s;          // P=0 -> first O/L MFMAs add exact 0
  vp0 = ones; vp1 = ones;          // finite (avoid NaN*0)

  kb[0][0] = *(const s16x8*)(kp);
  kb[0][1] = *(const s16x8*)(kp + 16 * HD);
  vb[0][0] = *(const s16x8*)(vp);
  vb[0][1] = *(const s16x8*)(vp + 16 * NPIX);
  kb[1][0] = *(const s16x8*)(kp + KT * HD);
  kb[1][1] = *(const s16x8*)(kp + KT * HD + 16 * HD);
  vb[1][0] = *(const s16x8*)(vp + KT);
  vb[1][1] = *(const s16x8*)(vp + KT + 16 * NPIX);

#define ATTN_STEP(CUR, NX2, T)                                                \
  {                                                                           \
    if ((T) + 2 < NTW) {                                                      \
      const short* kpn = kp + ((T) + 2) * (KT * HD);                          \
      const short* vpn = vp + ((T) + 2) * KT;                                 \
      kb[NX2][0] = *(const s16x8*)(kpn);                                      \
      kb[NX2][1] = *(const s16x8*)(kpn + 16 * HD);                            \
      vb[NX2][0] = *(const s16x8*)(vpn);                                      \
      vb[NX2][1] = *(const s16x8*)(vpn + 16 * NPIX);                          \
    }                                                                         \
    f32x4 SA0 = MFMA32(kb[CUR][0], qhA, Z4);                                  \
    f32x4 SA1 = MFMA32(kb[CUR][1], qhA, Z4);                                  \
    f32x4 SB0 = MFMA32(kb[CUR][0], qhB, Z4);                                  \
    f32x4 SB1 = MFMA32(kb[CUR][1], qhB, Z4);                                  \
    OA0 = MFMA32(vp0, pfA, OA0);                                              \
    OA1 = MFMA32(vp1, pfA, OA1);                                              \
    OB0 = MFMA32(vp0, pfB, OB0);                                              \
    OB1 = MFMA32(vp1, pfB, OB1);                                              \
    LA  = MFMA32(ones, pfA, LA);                                              \
    LB  = MFMA32(ones, pfB, LB);                                              \
    {                                                                         \
      f32x4 p0, p1;                                                           \
      p0[0] = exp2f(SA0[0]); p0[1] = exp2f(SA0[1]);                           \
      p0[2] = exp2f(SA0[2]); p0[3] = exp2f(SA0[3]);                           \
      p1[0] = exp2f(SA1[0]); p1[1] = exp2f(SA1[1]);                           \
      p1[2] = exp2f(SA1[2]); p1[3] = exp2f(SA1[3]);                           \
      uint2 w0, w1;                                                           \
      w0.x = pk2(rnau(p0[0]), rnau(p0[1])); w0.y = pk2(rnau(p0[2]), rnau(p0[3])); \
      w1.x = pk2(rnau(p1[0]), rnau(p1[1])); w1.y = pk2(rnau(p1[2]), rnau(p1[3])); \
      *(uint2*)&pwA[q * 40 + g * 4] = w0;                                     \
      *(uint2*)&pwA[q * 40 + 16 + g * 4] = w1;                                \
    }                                                                         \
    {                                                                         \
      f32x4 p0, p1;                                                           \
      p0[0] = exp2f(SB0[0]); p0[1] = exp2f(SB0[1]);                           \
      p0[2] = exp2f(SB0[2]); p0[3] = exp2f(SB0[3]);                           \
      p1[0] = exp2f(SB1[0]); p1[1] = exp2f(SB1[1]);                           \
      p1[2] = exp2f(SB1[2]); p1[3] = exp2f(SB1[3]);                           \
      uint2 w0, w1;                                                           \
      w0.x = pk2(rnau(p0[0]), rnau(p0[1])); w0.y = pk2(rnau(p0[2]), rnau(p0[3])); \
      w1.x = pk2(rnau(p1[0]), rnau(p1[1])); w1.y = pk2(rnau(p1[2]), rnau(p1[3])); \
      *(uint2*)&pwB[q * 40 + g * 4] = w0;                                     \
      *(uint2*)&pwB[q * 40 + 16 + g * 4] = w1;                                \
    }                                                                         \
    vp0 = vb[CUR][0]; vp1 = vb[CUR][1];                                       \
    pfA = *(const s16x8*)&pwA[q * 40 + g * 8];                                \
    pfB = *(const s16x8*)&pwB[q * 40 + g * 8];                                \
  }

#pragma unroll 1
  for (int tt = 0; tt < NTW; tt += 3) {
    ATTN_STEP(0, 2, tt);
    ATTN_STEP(1, 0, tt + 1);
    ATTN_STEP(2, 1, tt + 2);
  }
#undef ATTN_STEP

  // Tail: consume P of the wave's last tile
  OA0 = MFMA32(vp0, pfA, OA0);
  OA1 = MFMA32(vp1, pfA, OA1);
  OB0 = MFMA32(vp0, pfB, OB0);
  OB1 = MFMA32(vp1, pfB, OB1);
  LA  = MFMA32(ones, pfA, LA);
  LB  = MFMA32(ones, pfB, LB);

  // All waves done with P staging -> safe to alias as reduction buffer.
  __syncthreads();
  {
    float* rw = &R[wave][lane][0];
    *(f32x4*)&rw[0]  = OA0;   // d = g*4+r        (rows nA)
    *(f32x4*)&rw[4]  = OA1;   // d = 16+g*4+r
    *(f32x4*)&rw[8]  = OB0;   // d = g*4+r        (rows nB)
    *(f32x4*)&rw[12] = OB1;   // d = 16+g*4+r
    rw[16] = LA[0];           // L rows identical -> LA[0] = L[q-row A]
    rw[17] = LB[0];
  }
  __syncthreads();
  {
    // 512 threads: lane-slot l2 (same (g2,q2) mapping), eg in 0..7 picks
    // 2 O-elements: eg<4 -> A-half, else B-half; idx=(eg&3)*2 in the half.
    const int l2 = tid & 63, eg = tid >> 6;
    const int g2 = l2 >> 4, q2 = l2 & 15;
    const int isB = eg >> 2;
    const int idx = (eg & 3) * 2;
    float s0 = 0.f, s1 = 0.f, Lt = 0.f;
#pragma unroll
    for (int w = 0; w < NWAVE; ++w) {
      const float* rw = &R[w][l2][0];
      s0 += rw[isB * 8 + idx];
      s1 += rw[isB * 8 + idx + 1];
      Lt += rw[16 + isB];
    }
    const float inv = 1.f / Lt;
    const int h = bh & 7, b = bh >> 3;
    const int n = base + isB * 16 + q2;
    const int d0 = (idx < 4) ? (g2 * 4 + idx) : (16 + g2 * 4 + (idx - 4));
    const int c = n / 9, r = n - c * 9;
    short* zp = zh + ((size_t)(b * NPIX + r * 256 + h * HD + d0)) * DIMC + c;
    zp[0]    = (short)(rnau(s0 * inv) >> 16);
    zp[DIMC] = (short)(rnau(s1 * inv) >> 16);
  }
}

// ---------------------------------------------------------------------------
// PROJ GEMM: single MFMA/tile (Wh*Zh). fp32 out + bias. UNCHANGED.
// ---------------------------------------------------------------------------
__global__ __launch_bounds__(128) void gemm_proj_hi(
    const short* __restrict__ Wh,
    const float* __restrict__ bias,
    const short* __restrict__ Zh,
    float* __restrict__ out) {
  __shared__ __align__(16) float Cl[32][68];
  const int n0 = blockIdx.x * 64;
  const int o0 = blockIdx.y * 32;
  const int b  = blockIdx.z;
  const int tid = threadIdx.x;
  const int wave = tid >> 6, lane = tid & 63;
  const int g = lane >> 4, q = lane & 15;

  const short* wph = Wh + ((o0 + wave * 16 + q) * DIMC + g * 8);
  const short* iph = Zh + ((size_t)(b * NPIX + n0 + q) * DIMC + g * 8);

  f32x4 acc[4] = {{0,0,0,0},{0,0,0,0},{0,0,0,0},{0,0,0,0}};
#pragma unroll
  for (int c0 = 0; c0 < DIMC; c0 += 32) {
    s16x8 ah = *(const s16x8*)(wph + c0);
#pragma unroll
    for (int st = 0; st < 4; ++st) {
      s16x8 bh_ = *(const s16x8*)(iph + (size_t)st * 16 * DIMC + c0);
      acc[st] = MFMA32(ah, bh_, acc[st]);
    }
  }
#pragma unroll
  for (int st = 0; st < 4; ++st)
#pragma unroll
    for (int r = 0; r < 4; ++r)
      Cl[wave * 16 + g * 4 + r][st * 16 + q] = acc[st][r];
  __syncthreads();

  const int o = tid >> 2, nc = (tid & 3) * 16;
  const float bv = bias[o0 + o];
  float* op = out + ((size_t)b * DIMC + o0 + o) * NPIX + n0 + nc;
#pragma unroll
  for (int i2 = 0; i2 < 4; ++i2) {
    f32x4 v = *(const f32x4*)&Cl[o][nc + i2 * 4];
    v[0] += bv; v[1] += bv; v[2] += bv; v[3] += bv;
    *(f32x4*)(op + i2 * 4) = v;
  }
}

// ---------------------------------------------------------------------------
extern "C" void kernel_launch(void* const* d_in, const int* in_sizes, int n_in,
                              void* d_out, int out_size, void* d_ws, size_t ws_size,
                              hipStream_t stream) {
  const float* x      = (const float*)d_in[0];
  const float* q_w    = (const float*)d_in[1];
  const float* q_b    = (const float*)d_in[2];
  const float* kv_w   = (const float*)d_in[3];
  const float* kv_b   = (const float*)d_in[4];
  const float* proj_w = (const float*)d_in[5];
  const float* proj_b = (const float*)d_in[6];
  float* out = (float*)d_out;

  // Workspace (offsets preserved).
  char* w = (char*)d_ws;
  float* xavg = (float*)w;                       // 4,718,592
  short* Xh   = (short*)(w + 4718592);
  short* Ah   = (short*)(w + 9437184);
  short* Wth  = (short*)(w + 28311552);          // 524,288 (hi only)
  short* Qhi  = (short*)(w + 29360128);          // 2,359,296
  short* Khi  = (short*)(w + 31719424);
  short* Vhi  = (short*)(w + 34078720);
  short* Zh   = (short*)(w + 37322752);          // 2,359,296

  const float qscale = 0.17677669529663689f * 1.4426950408889634f; // d^-0.5*log2(e)

  pool_kernel<<<BATCH * DIMC, 256, 0, stream>>>(x, xavg);
  conv_all<<<704, 256, 0, stream>>>(x, xavg, q_w, kv_w, proj_w, Xh, Ah, Wth);
  gemm_qkv_hi<<<dim3(36, 24, 2), 128, 0, stream>>>(Wth, q_b, kv_b,
                                                   Xh, Ah, Qhi, Khi, Vhi, qscale);
  attn_fused<<<1152, 512, 0, stream>>>(Qhi, Khi, Vhi, Zh);
  gemm_proj_hi<<<dim3(36, 8, 2), 128, 0, stream>>>(Wth + 196608, proj_b, Zh, out);
}

// Round 6
// 148.674 us; speedup vs baseline: 1.8540x; 1.0520x over previous
//
#include <hip/hip_runtime.h>
#include <hip/hip_bf16.h>
#include <cstdint>

// Problem constants
#define DIMC  256
#define NH    8
#define HD    32
#define NPIX  2304       // 48*48
#define BATCH 2
#define KT    32
#define NWAVE 4          // waves per attn block
#define NTW   18         // k-tiles per wave (72 tiles / 4 waves)
#define KPW   576        // keys per wave (NTW*KT)

typedef short s16x8 __attribute__((ext_vector_type(8)));
typedef short s16x4 __attribute__((ext_vector_type(4)));
typedef float f32x4 __attribute__((ext_vector_type(4)));

#define MFMA32(A,B,C) __builtin_amdgcn_mfma_f32_16x16x32_bf16(A,B,C,0,0,0)

// RNA (round-to-nearest-away) bf16 helpers: 1 VALU each.
__device__ inline uint32_t rnau(float x) { return __float_as_uint(x) + 0x8000u; }
__device__ inline uint32_t pk2(uint32_t l_, uint32_t h_) {
  return __builtin_amdgcn_perm(h_, l_, 0x07060302u);  // lo short=l_, hi short=h_
}

// ---------------------------------------------------------------------------
// Pool: x_avg = (x + box3/9 + box5/25 + box7/49)/4, zero-pad, include_pad
// ---------------------------------------------------------------------------
__global__ __launch_bounds__(256) void pool_kernel(const float* __restrict__ x,
                                                   float* __restrict__ xavg) {
  const int plane = blockIdx.x;
  const float* xp = x + (size_t)plane * NPIX;
  __shared__ float sx[NPIX];
  __shared__ float h3[NPIX], h5[NPIX], h7[NPIX];
  const int t = threadIdx.x;
#pragma unroll
  for (int r = 0; r < 9; ++r) sx[r * 256 + t] = xp[r * 256 + t];
  __syncthreads();
#pragma unroll
  for (int r = 0; r < 9; ++r) {
    int p = r * 256 + t;
    int i = p / 48, j = p - i * 48;
    float a3 = 0.f, a5 = 0.f, a7 = 0.f;
#pragma unroll
    for (int dj = -3; dj <= 3; ++dj) {
      int jj = j + dj;
      if (jj < 0 || jj >= 48) continue;
      float v = sx[i * 48 + jj];
      a7 += v;
      if (dj >= -2 && dj <= 2) a5 += v;
      if (dj >= -1 && dj <= 1) a3 += v;
    }
    h3[p] = a3; h5[p] = a5; h7[p] = a7;
  }
  __syncthreads();
#pragma unroll
  for (int r = 0; r < 9; ++r) {
    int p = r * 256 + t;
    int i = p / 48, j = p - i * 48;
    float b3 = 0.f, b5 = 0.f, b7 = 0.f;
#pragma unroll
    for (int di = -3; di <= 3; ++di) {
      int ii = i + di;
      if (ii < 0 || ii >= 48) continue;
      int q = ii * 48 + j;
      b7 += h7[q];
      if (di >= -2 && di <= 2) b5 += h5[q];
      if (di >= -1 && di <= 1) b3 += h3[q];
    }
    xavg[(size_t)plane * NPIX + p] =
        0.25f * (sx[p] + b3 * (1.f / 9.f) + b5 * (1.f / 25.f) + b7 * (1.f / 49.f));
  }
}

// ---------------------------------------------------------------------------
// Fused converts: blocks 0..287 tconv(x), 288..575 tconv(xavg), 576..703 wconv
// All HI-ONLY. UNCHANGED.
// ---------------------------------------------------------------------------
__global__ __launch_bounds__(256) void conv_all(
    const float* __restrict__ x, const float* __restrict__ xavg,
    const float* __restrict__ qw, const float* __restrict__ kvw,
    const float* __restrict__ pw_,
    short* __restrict__ Xh, short* __restrict__ Ah,
    short* __restrict__ Wth) {
  const int bx = blockIdx.x;
  const int t = threadIdx.x;
  if (bx < 576) {
    const float* src = (bx < 288) ? x : xavg;
    short* dhi = (bx < 288) ? Xh : Ah;
    const int bb = (bx < 288) ? bx : bx - 288;
    const int n0 = (bb % 36) * 64, c0 = ((bb / 36) & 3) * 64, b = bb / 144;
    __shared__ __align__(16) float T[64][68];
    {
      const int c = t >> 2, n4 = (t & 3) * 16;
      const float* sp = src + ((size_t)b * DIMC + c0 + c) * NPIX + n0 + n4;
#pragma unroll
      for (int i2 = 0; i2 < 4; ++i2)
        *(f32x4*)&T[c][n4 + i2 * 4] = *(const f32x4*)(sp + i2 * 4);
    }
    __syncthreads();
    {
      const int n = t >> 2, c4 = (t & 3) * 16;
      float v[16];
#pragma unroll
      for (int i = 0; i < 16; ++i) v[i] = T[c4 + i][n];
      uint32_t a[16];
#pragma unroll
      for (int i = 0; i < 16; ++i) a[i] = rnau(v[i]);
      union { s16x8 s; uint32_t u[4]; } H0, H1;
#pragma unroll
      for (int j = 0; j < 4; ++j) {
        H0.u[j] = pk2(a[2 * j], a[2 * j + 1]);
        H1.u[j] = pk2(a[8 + 2 * j], a[8 + 2 * j + 1]);
      }
      const size_t off = ((size_t)b * NPIX + n0 + n) * DIMC + c0 + c4;
      *(s16x8*)(dhi + off) = H0.s; *(s16x8*)(dhi + off + 8) = H1.s;
    }
  } else {
    const int idx = ((bx - 576) * 256 + t) * 8;
    const float* s;
    int off;
    if (idx < 65536)       { s = qw;  off = idx; }
    else if (idx < 196608) { s = kvw; off = idx - 65536; }
    else                   { s = pw_; off = idx - 196608; }
    f32x4 x0 = *(const f32x4*)(s + off);
    f32x4 x1 = *(const f32x4*)(s + off + 4);
    float v[8] = {x0[0], x0[1], x0[2], x0[3], x1[0], x1[1], x1[2], x1[3]};
    uint32_t a[8];
#pragma unroll
    for (int i = 0; i < 8; ++i) a[i] = rnau(v[i]);
    union { s16x8 s; uint32_t u[4]; } H;
#pragma unroll
    for (int j = 0; j < 4; ++j) H.u[j] = pk2(a[2 * j], a[2 * j + 1]);
    *(s16x8*)(Wth + idx) = H.s;
  }
}

// ---------------------------------------------------------------------------
// QKV GEMM: single MFMA/tile (Wh*Xh). UNCHANGED.
// ---------------------------------------------------------------------------
__global__ __launch_bounds__(128) void gemm_qkv_hi(
    const short* __restrict__ Wth,
    const float* __restrict__ q_b, const float* __restrict__ kv_b,
    const short* __restrict__ Xh, const short* __restrict__ Ah,
    short* __restrict__ Qhi, short* __restrict__ Khi, short* __restrict__ Vhi,
    float qscale) {
  __shared__ __align__(16) float Cl[32][68];
  const int by = blockIdx.y;
  const bool isQ = (by < 8);
  const int o0 = isQ ? by * 32 : (by - 8) * 32;
  const short* Wh = isQ ? Wth : Wth + 65536;
  const float* bias = isQ ? q_b : kv_b;
  const short* Inh = isQ ? Xh : Ah;
  const float scale = isQ ? qscale : 1.0f;
  short* d1 = isQ ? Qhi : Khi;   // used when o0 < 256 (Q or K)
  const int n0 = blockIdx.x * 64;
  const int b  = blockIdx.z;

  const int tid = threadIdx.x;
  const int wave = tid >> 6, lane = tid & 63;
  const int g = lane >> 4, q = lane & 15;

  const short* wph = Wh + ((o0 + wave * 16 + q) * DIMC + g * 8);
  const short* iph = Inh + ((size_t)(b * NPIX + n0 + q) * DIMC + g * 8);

  f32x4 acc[4] = {{0,0,0,0},{0,0,0,0},{0,0,0,0},{0,0,0,0}};
#pragma unroll
  for (int c0 = 0; c0 < DIMC; c0 += 32) {
    s16x8 ah = *(const s16x8*)(wph + c0);
#pragma unroll
    for (int st = 0; st < 4; ++st) {
      s16x8 bh_ = *(const s16x8*)(iph + (size_t)st * 16 * DIMC + c0);
      acc[st] = MFMA32(ah, bh_, acc[st]);
    }
  }
#pragma unroll
  for (int st = 0; st < 4; ++st)
#pragma unroll
    for (int r = 0; r < 4; ++r)
      Cl[wave * 16 + g * 4 + r][st * 16 + q] = acc[st][r];
  __syncthreads();

  if (o0 < 256) {
    // Q or K: (C+bias)*scale, hi-only, layout [bh][n][32]
    const int n = tid >> 1, oq = tid & 1;
    const int h = o0 >> 5;
    const float* bp = bias + o0 + oq * 16;
    float v[16];
#pragma unroll
    for (int i = 0; i < 16; ++i) v[i] = (Cl[oq * 16 + i][n] + bp[i]) * scale;
    uint32_t a[16];
#pragma unroll
    for (int i = 0; i < 16; ++i) a[i] = rnau(v[i]);
    union { s16x8 s; uint32_t u[4]; } H0, H1;
#pragma unroll
    for (int j = 0; j < 4; ++j) {
      H0.u[j] = pk2(a[2 * j], a[2 * j + 1]);
      H1.u[j] = pk2(a[8 + 2 * j], a[8 + 2 * j + 1]);
    }
    const size_t off = ((size_t)((b * 8 + h) * NPIX + n0 + n)) * HD + oq * 16;
    *(s16x8*)(d1 + off) = H0.s; *(s16x8*)(d1 + off + 8) = H1.s;
  } else {
    // V hi-only: dst [bh][d][n]
    const int o = tid >> 2, nc = (tid & 3) * 16;
    const int h = (o0 - 256) >> 5;
    const float bv = bias[o0 + o];
    float v[16];
#pragma unroll
    for (int i2 = 0; i2 < 4; ++i2) {
      f32x4 t4 = *(const f32x4*)&Cl[o][nc + i2 * 4];
      v[i2 * 4 + 0] = t4[0] + bv; v[i2 * 4 + 1] = t4[1] + bv;
      v[i2 * 4 + 2] = t4[2] + bv; v[i2 * 4 + 3] = t4[3] + bv;
    }
    uint32_t a[16];
#pragma unroll
    for (int i = 0; i < 16; ++i) a[i] = rnau(v[i]);
    union { s16x8 s; uint32_t u[4]; } H0, H1;
#pragma unroll
    for (int j = 0; j < 4; ++j) {
      H0.u[j] = pk2(a[2 * j], a[2 * j + 1]);
      H1.u[j] = pk2(a[8 + 2 * j], a[8 + 2 * j + 1]);
    }
    const size_t off = ((size_t)((b * 8 + h) * HD + o)) * NPIX + n0 + nc;
    *(s16x8*)(Vhi + off) = H0.s; *(s16x8*)(Vhi + off + 8) = H1.s;
  }
}

// ---------------------------------------------------------------------------
// MFMA flash attention: R2's proven 4-wave/18-tile body + R4's proven
// XCD-aware swizzle. Block = 4 waves over the SAME 32 q-rows; wave w owns
// k-tiles [w*18, w*18+18). Partial O (f32) + L reduced via LDS (aliased
// over P staging), normalized, written directly in the torch-scramble
// layout z[b][(n%9)*256 + h*32 + d][n/9].
// Swizzle: bh = 2*(li&7) + (li>>3)/72 -> each bh-pair's 144 blocks on one
// XCD (HW round-robins blockIdx%8): K/V stays L2-resident (R4: FETCH 3.5MB).
// No min-waves clamp (R3 lesson: (512,6) caused a 70-reg spill).
// ---------------------------------------------------------------------------
__global__ __launch_bounds__(256) void attn_fused(
    const short* __restrict__ Qhi,   // [bh][n][32]
    const short* __restrict__ Khi,   // [bh][n][32]
    const short* __restrict__ Vhi,   // [bh][32][N]
    short* __restrict__ zh) {        // [b][pix][256] scrambled
  const int li = blockIdx.x;         // 0..1151
  const int r144 = li >> 3;          // 0..143
  const int bh = 2 * (li & 7) + (r144 >= 72 ? 1 : 0);
  const int qb = (r144 >= 72) ? r144 - 72 : r144;  // 32-row q block
  const int tid = threadIdx.x;
  const int wave = tid >> 6, lane = tid & 63;
  const int g = lane >> 4, q = lane & 15;
  const int base = qb * 32;

  // smem: phase 1 = P staging [4 waves][2 bufs][16*40 shorts] (10240 B)
  //       phase 2 = reduction  [4 waves][64 lanes][20 f32]    (20480 B)
  __shared__ __align__(16) float smemf[4 * 64 * 20];
  short* pwA = (short*)smemf + wave * 1280;
  short* pwB = pwA + 640;
  float (*R)[64][20] = (float (*)[64][20])smemf;

  const size_t qoff = ((size_t)bh * NPIX + base + q) * HD + g * 8;
  const s16x8 qhA = *(const s16x8*)(Qhi + qoff);
  const s16x8 qhB = *(const s16x8*)(Qhi + qoff + 16 * HD);

  const short* kp = Khi + ((size_t)bh * NPIX + wave * KPW + q) * HD + g * 8;
  const short* vp = Vhi + ((size_t)bh * HD + q) * NPIX + wave * KPW + g * 8;

  const f32x4 Z4 = {0.f, 0.f, 0.f, 0.f};
  f32x4 OA0 = Z4, OA1 = Z4, OB0 = Z4, OB1 = Z4;
  f32x4 LA = Z4, LB = Z4;
  s16x8 kb[3][2], vb[3][2], pfA, pfB, vp0, vp1;

  union { s16x8 s; uint32_t u[4]; } ONE, ZZ;
  ONE.u[0] = 0x3F803F80u; ONE.u[1] = 0x3F803F80u;
  ONE.u[2] = 0x3F803F80u; ONE.u[3] = 0x3F803F80u;
  ZZ.u[0] = 0; ZZ.u[1] = 0; ZZ.u[2] = 0; ZZ.u[3] = 0;
  const s16x8 ones = ONE.s;
  pfA = ZZ.s; pfB = ZZ.s;          // P=0 -> first O/L MFMAs add exact 0
  vp0 = ones; vp1 = ones;          // finite (avoid NaN*0)

  kb[0][0] = *(const s16x8*)(kp);
  kb[0][1] = *(const s16x8*)(kp + 16 * HD);
  vb[0][0] = *(const s16x8*)(vp);
  vb[0][1] = *(const s16x8*)(vp + 16 * NPIX);
  kb[1][0] = *(const s16x8*)(kp + KT * HD);
  kb[1][1] = *(const s16x8*)(kp + KT * HD + 16 * HD);
  vb[1][0] = *(const s16x8*)(vp + KT);
  vb[1][1] = *(const s16x8*)(vp + KT + 16 * NPIX);

#define ATTN_STEP(CUR, NX2, T)                                                \
  {                                                                           \
    if ((T) + 2 < NTW) {                                                      \
      const short* kpn = kp + ((T) + 2) * (KT * HD);                          \
      const short* vpn = vp + ((T) + 2) * KT;                                 \
      kb[NX2][0] = *(const s16x8*)(kpn);                                      \
      kb[NX2][1] = *(const s16x8*)(kpn + 16 * HD);                            \
      vb[NX2][0] = *(const s16x8*)(vpn);                                      \
      vb[NX2][1] = *(const s16x8*)(vpn + 16 * NPIX);                          \
    }                                                                         \
    f32x4 SA0 = MFMA32(kb[CUR][0], qhA, Z4);                                  \
    f32x4 SA1 = MFMA32(kb[CUR][1], qhA, Z4);                                  \
    f32x4 SB0 = MFMA32(kb[CUR][0], qhB, Z4);                                  \
    f32x4 SB1 = MFMA32(kb[CUR][1], qhB, Z4);                                  \
    OA0 = MFMA32(vp0, pfA, OA0);                                              \
    OA1 = MFMA32(vp1, pfA, OA1);                                              \
    OB0 = MFMA32(vp0, pfB, OB0);                                              \
    OB1 = MFMA32(vp1, pfB, OB1);                                              \
    LA  = MFMA32(ones, pfA, LA);                                              \
    LB  = MFMA32(ones, pfB, LB);                                              \
    {                                                                         \
      f32x4 p0, p1;                                                           \
      p0[0] = exp2f(SA0[0]); p0[1] = exp2f(SA0[1]);                           \
      p0[2] = exp2f(SA0[2]); p0[3] = exp2f(SA0[3]);                           \
      p1[0] = exp2f(SA1[0]); p1[1] = exp2f(SA1[1]);                           \
      p1[2] = exp2f(SA1[2]); p1[3] = exp2f(SA1[3]);                           \
      uint2 w0, w1;                                                           \
      w0.x = pk2(rnau(p0[0]), rnau(p0[1])); w0.y = pk2(rnau(p0[2]), rnau(p0[3])); \
      w1.x = pk2(rnau(p1[0]), rnau(p1[1])); w1.y = pk2(rnau(p1[2]), rnau(p1[3])); \
      *(uint2*)&pwA[q * 40 + g * 4] = w0;                                     \
      *(uint2*)&pwA[q * 40 + 16 + g * 4] = w1;                                \
    }                                                                         \
    {                                                                         \
      f32x4 p0, p1;                                                           \
      p0[0] = exp2f(SB0[0]); p0[1] = exp2f(SB0[1]);                           \
      p0[2] = exp2f(SB0[2]); p0[3] = exp2f(SB0[3]);                           \
      p1[0] = exp2f(SB1[0]); p1[1] = exp2f(SB1[1]);                           \
      p1[2] = exp2f(SB1[2]); p1[3] = exp2f(SB1[3]);                           \
      uint2 w0, w1;                                                           \
      w0.x = pk2(rnau(p0[0]), rnau(p0[1])); w0.y = pk2(rnau(p0[2]), rnau(p0[3])); \
      w1.x = pk2(rnau(p1[0]), rnau(p1[1])); w1.y = pk2(rnau(p1[2]), rnau(p1[3])); \
      *(uint2*)&pwB[q * 40 + g * 4] = w0;                                     \
      *(uint2*)&pwB[q * 40 + 16 + g * 4] = w1;                                \
    }                                                                         \
    vp0 = vb[CUR][0]; vp1 = vb[CUR][1];                                       \
    pfA = *(const s16x8*)&pwA[q * 40 + g * 8];                                \
    pfB = *(const s16x8*)&pwB[q * 40 + g * 8];                                \
  }

#pragma unroll 1
  for (int tt = 0; tt < NTW; tt += 3) {
    ATTN_STEP(0, 2, tt);
    ATTN_STEP(1, 0, tt + 1);
    ATTN_STEP(2, 1, tt + 2);
  }
#undef ATTN_STEP

  // Tail: consume P of the wave's last tile
  OA0 = MFMA32(vp0, pfA, OA0);
  OA1 = MFMA32(vp1, pfA, OA1);
  OB0 = MFMA32(vp0, pfB, OB0);
  OB1 = MFMA32(vp1, pfB, OB1);
  LA  = MFMA32(ones, pfA, LA);
  LB  = MFMA32(ones, pfB, LB);

  // All waves done with P staging -> safe to alias as reduction buffer.
  __syncthreads();
  {
    float* rw = &R[wave][lane][0];
    *(f32x4*)&rw[0]  = OA0;   // d = g*4+r        (rows nA)
    *(f32x4*)&rw[4]  = OA1;   // d = 16+g*4+r
    *(f32x4*)&rw[8]  = OB0;   // d = g*4+r        (rows nB)
    *(f32x4*)&rw[12] = OB1;   // d = 16+g*4+r
    rw[16] = LA[0];           // L rows identical -> LA[0] = L[q-row A]
    rw[17] = LB[0];
  }
  __syncthreads();
  {
    // 256 threads: lane-slot l2, element group eg (4 O-elems each).
    const int l2 = tid & 63, eg = tid >> 6;
    const int g2 = l2 >> 4, q2 = l2 & 15;
    f32x4 s = {0.f, 0.f, 0.f, 0.f};
    float Lt = 0.f;
#pragma unroll
    for (int w = 0; w < NWAVE; ++w) {
      const f32x4 pv = *(const f32x4*)&R[w][l2][eg * 4];
      s[0] += pv[0]; s[1] += pv[1]; s[2] += pv[2]; s[3] += pv[3];
      Lt += R[w][l2][16 + (eg >> 1)];
    }
    const float inv = 1.f / Lt;
    const int h = bh & 7, b = bh >> 3;
    const int n = base + ((eg & 2) ? 16 : 0) + q2;
    const int d0 = ((eg & 1) ? 16 : 0) + g2 * 4;
    const int c = n / 9, r = n - c * 9;
    short* zp = zh + ((size_t)(b * NPIX + r * 256 + h * HD + d0)) * DIMC + c;
#pragma unroll
    for (int j = 0; j < 4; ++j)
      zp[(size_t)j * DIMC] = (short)(rnau(s[j] * inv) >> 16);
  }
}

// ---------------------------------------------------------------------------
// PROJ GEMM: single MFMA/tile (Wh*Zh). fp32 out + bias. UNCHANGED.
// ---------------------------------------------------------------------------
__global__ __launch_bounds__(128) void gemm_proj_hi(
    const short* __restrict__ Wh,
    const float* __restrict__ bias,
    const short* __restrict__ Zh,
    float* __restrict__ out) {
  __shared__ __align__(16) float Cl[32][68];
  const int n0 = blockIdx.x * 64;
  const int o0 = blockIdx.y * 32;
  const int b  = blockIdx.z;
  const int tid = threadIdx.x;
  const int wave = tid >> 6, lane = tid & 63;
  const int g = lane >> 4, q = lane & 15;

  const short* wph = Wh + ((o0 + wave * 16 + q) * DIMC + g * 8);
  const short* iph = Zh + ((size_t)(b * NPIX + n0 + q) * DIMC + g * 8);

  f32x4 acc[4] = {{0,0,0,0},{0,0,0,0},{0,0,0,0},{0,0,0,0}};
#pragma unroll
  for (int c0 = 0; c0 < DIMC; c0 += 32) {
    s16x8 ah = *(const s16x8*)(wph + c0);
#pragma unroll
    for (int st = 0; st < 4; ++st) {
      s16x8 bh_ = *(const s16x8*)(iph + (size_t)st * 16 * DIMC + c0);
      acc[st] = MFMA32(ah, bh_, acc[st]);
    }
  }
#pragma unroll
  for (int st = 0; st < 4; ++st)
#pragma unroll
    for (int r = 0; r < 4; ++r)
      Cl[wave * 16 + g * 4 + r][st * 16 + q] = acc[st][r];
  __syncthreads();

  const int o = tid >> 2, nc = (tid & 3) * 16;
  const float bv = bias[o0 + o];
  float* op = out + ((size_t)b * DIMC + o0 + o) * NPIX + n0 + nc;
#pragma unroll
  for (int i2 = 0; i2 < 4; ++i2) {
    f32x4 v = *(const f32x4*)&Cl[o][nc + i2 * 4];
    v[0] += bv; v[1] += bv; v[2] += bv; v[3] += bv;
    *(f32x4*)(op + i2 * 4) = v;
  }
}

// ---------------------------------------------------------------------------
extern "C" void kernel_launch(void* const* d_in, const int* in_sizes, int n_in,
                              void* d_out, int out_size, void* d_ws, size_t ws_size,
                              hipStream_t stream) {
  const float* x      = (const float*)d_in[0];
  const float* q_w    = (const float*)d_in[1];
  const float* q_b    = (const float*)d_in[2];
  const float* kv_w   = (const float*)d_in[3];
  const float* kv_b   = (const float*)d_in[4];
  const float* proj_w = (const float*)d_in[5];
  const float* proj_b = (const float*)d_in[6];
  float* out = (float*)d_out;

  // Workspace (offsets preserved).
  char* w = (char*)d_ws;
  float* xavg = (float*)w;                       // 4,718,592
  short* Xh   = (short*)(w + 4718592);
  short* Ah   = (short*)(w + 9437184);
  short* Wth  = (short*)(w + 28311552);          // 524,288 (hi only)
  short* Qhi  = (short*)(w + 29360128);          // 2,359,296
  short* Khi  = (short*)(w + 31719424);
  short* Vhi  = (short*)(w + 34078720);
  short* Zh   = (short*)(w + 37322752);          // 2,359,296

  const float qscale = 0.17677669529663689f * 1.4426950408889634f; // d^-0.5*log2(e)

  pool_kernel<<<BATCH * DIMC, 256, 0, stream>>>(x, xavg);
  conv_all<<<704, 256, 0, stream>>>(x, xavg, q_w, kv_w, proj_w, Xh, Ah, Wth);
  gemm_qkv_hi<<<dim3(36, 24, 2), 128, 0, stream>>>(Wth, q_b, kv_b,
                                                   Xh, Ah, Qhi, Khi, Vhi, qscale);
  attn_fused<<<1152, 256, 0, stream>>>(Qhi, Khi, Vhi, Zh);
  gemm_proj_hi<<<dim3(36, 8, 2), 128, 0, stream>>>(Wth + 196608, proj_b, Zh, out);
}

// Round 7
// 147.865 us; speedup vs baseline: 1.8642x; 1.0055x over previous
//
#include <hip/hip_runtime.h>
#include <hip/hip_bf16.h>
#include <cstdint>

// Problem constants
#define DIMC  256
#define NH    8
#define HD    32
#define NPIX  2304       // 48*48
#define BATCH 2
#define KT    32
#define NWAVE 4          // waves per attn block
#define NTW   18         // k-tiles per wave (72 tiles / 4 waves)
#define KPW   576        // keys per wave (NTW*KT)

typedef short s16x8 __attribute__((ext_vector_type(8)));
typedef short s16x4 __attribute__((ext_vector_type(4)));
typedef float f32x4 __attribute__((ext_vector_type(4)));

#define MFMA32(A,B,C) __builtin_amdgcn_mfma_f32_16x16x32_bf16(A,B,C,0,0,0)

// RNA (round-to-nearest-away) bf16 helpers: 1 VALU each.
__device__ inline uint32_t rnau(float x) { return __float_as_uint(x) + 0x8000u; }
__device__ inline uint32_t pk2(uint32_t l_, uint32_t h_) {
  return __builtin_amdgcn_perm(h_, l_, 0x07060302u);  // lo short=l_, hi short=h_
}

// ---------------------------------------------------------------------------
// Pool: x_avg = (x + box3/9 + box5/25 + box7/49)/4, zero-pad, include_pad
// ---------------------------------------------------------------------------
__global__ __launch_bounds__(256) void pool_kernel(const float* __restrict__ x,
                                                   float* __restrict__ xavg) {
  const int plane = blockIdx.x;
  const float* xp = x + (size_t)plane * NPIX;
  __shared__ float sx[NPIX];
  __shared__ float h3[NPIX], h5[NPIX], h7[NPIX];
  const int t = threadIdx.x;
#pragma unroll
  for (int r = 0; r < 9; ++r) sx[r * 256 + t] = xp[r * 256 + t];
  __syncthreads();
#pragma unroll
  for (int r = 0; r < 9; ++r) {
    int p = r * 256 + t;
    int i = p / 48, j = p - i * 48;
    float a3 = 0.f, a5 = 0.f, a7 = 0.f;
#pragma unroll
    for (int dj = -3; dj <= 3; ++dj) {
      int jj = j + dj;
      if (jj < 0 || jj >= 48) continue;
      float v = sx[i * 48 + jj];
      a7 += v;
      if (dj >= -2 && dj <= 2) a5 += v;
      if (dj >= -1 && dj <= 1) a3 += v;
    }
    h3[p] = a3; h5[p] = a5; h7[p] = a7;
  }
  __syncthreads();
#pragma unroll
  for (int r = 0; r < 9; ++r) {
    int p = r * 256 + t;
    int i = p / 48, j = p - i * 48;
    float b3 = 0.f, b5 = 0.f, b7 = 0.f;
#pragma unroll
    for (int di = -3; di <= 3; ++di) {
      int ii = i + di;
      if (ii < 0 || ii >= 48) continue;
      int q = ii * 48 + j;
      b7 += h7[q];
      if (di >= -2 && di <= 2) b5 += h5[q];
      if (di >= -1 && di <= 1) b3 += h3[q];
    }
    xavg[(size_t)plane * NPIX + p] =
        0.25f * (sx[p] + b3 * (1.f / 9.f) + b5 * (1.f / 25.f) + b7 * (1.f / 49.f));
  }
}

// ---------------------------------------------------------------------------
// Fused converts: blocks 0..287 tconv(x), 288..575 tconv(xavg), 576..703 wconv
// All HI-ONLY. UNCHANGED.
// ---------------------------------------------------------------------------
__global__ __launch_bounds__(256) void conv_all(
    const float* __restrict__ x, const float* __restrict__ xavg,
    const float* __restrict__ qw, const float* __restrict__ kvw,
    const float* __restrict__ pw_,
    short* __restrict__ Xh, short* __restrict__ Ah,
    short* __restrict__ Wth) {
  const int bx = blockIdx.x;
  const int t = threadIdx.x;
  if (bx < 576) {
    const float* src = (bx < 288) ? x : xavg;
    short* dhi = (bx < 288) ? Xh : Ah;
    const int bb = (bx < 288) ? bx : bx - 288;
    const int n0 = (bb % 36) * 64, c0 = ((bb / 36) & 3) * 64, b = bb / 144;
    __shared__ __align__(16) float T[64][68];
    {
      const int c = t >> 2, n4 = (t & 3) * 16;
      const float* sp = src + ((size_t)b * DIMC + c0 + c) * NPIX + n0 + n4;
#pragma unroll
      for (int i2 = 0; i2 < 4; ++i2)
        *(f32x4*)&T[c][n4 + i2 * 4] = *(const f32x4*)(sp + i2 * 4);
    }
    __syncthreads();
    {
      const int n = t >> 2, c4 = (t & 3) * 16;
      float v[16];
#pragma unroll
      for (int i = 0; i < 16; ++i) v[i] = T[c4 + i][n];
      uint32_t a[16];
#pragma unroll
      for (int i = 0; i < 16; ++i) a[i] = rnau(v[i]);
      union { s16x8 s; uint32_t u[4]; } H0, H1;
#pragma unroll
      for (int j = 0; j < 4; ++j) {
        H0.u[j] = pk2(a[2 * j], a[2 * j + 1]);
        H1.u[j] = pk2(a[8 + 2 * j], a[8 + 2 * j + 1]);
      }
      const size_t off = ((size_t)b * NPIX + n0 + n) * DIMC + c0 + c4;
      *(s16x8*)(dhi + off) = H0.s; *(s16x8*)(dhi + off + 8) = H1.s;
    }
  } else {
    const int idx = ((bx - 576) * 256 + t) * 8;
    const float* s;
    int off;
    if (idx < 65536)       { s = qw;  off = idx; }
    else if (idx < 196608) { s = kvw; off = idx - 65536; }
    else                   { s = pw_; off = idx - 196608; }
    f32x4 x0 = *(const f32x4*)(s + off);
    f32x4 x1 = *(const f32x4*)(s + off + 4);
    float v[8] = {x0[0], x0[1], x0[2], x0[3], x1[0], x1[1], x1[2], x1[3]};
    uint32_t a[8];
#pragma unroll
    for (int i = 0; i < 8; ++i) a[i] = rnau(v[i]);
    union { s16x8 s; uint32_t u[4]; } H;
#pragma unroll
    for (int j = 0; j < 4; ++j) H.u[j] = pk2(a[2 * j], a[2 * j + 1]);
    *(s16x8*)(Wth + idx) = H.s;
  }
}

// ---------------------------------------------------------------------------
// QKV GEMM. Q/K epilogues unchanged. V epilogue now writes the n-dimension
// PERMUTED within each 32-key tile (bijection mu):
//   stored pos p = 8g+r   holds logical key 4g+r
//   stored pos p = 8g+4+r holds logical key 16+4g+r
// This makes attn's S-output fragment (lane k = {4g+r, 16+4g+r}) directly
// usable as the PV MFMA B-operand (k = 8g..8g+7) with NO redistribution.
// ---------------------------------------------------------------------------
__global__ __launch_bounds__(128) void gemm_qkv_hi(
    const short* __restrict__ Wth,
    const float* __restrict__ q_b, const float* __restrict__ kv_b,
    const short* __restrict__ Xh, const short* __restrict__ Ah,
    short* __restrict__ Qhi, short* __restrict__ Khi, short* __restrict__ Vhi,
    float qscale) {
  __shared__ __align__(16) float Cl[32][68];
  const int by = blockIdx.y;
  const bool isQ = (by < 8);
  const int o0 = isQ ? by * 32 : (by - 8) * 32;
  const short* Wh = isQ ? Wth : Wth + 65536;
  const float* bias = isQ ? q_b : kv_b;
  const short* Inh = isQ ? Xh : Ah;
  const float scale = isQ ? qscale : 1.0f;
  short* d1 = isQ ? Qhi : Khi;   // used when o0 < 256 (Q or K)
  const int n0 = blockIdx.x * 64;
  const int b  = blockIdx.z;

  const int tid = threadIdx.x;
  const int wave = tid >> 6, lane = tid & 63;
  const int g = lane >> 4, q = lane & 15;

  const short* wph = Wh + ((o0 + wave * 16 + q) * DIMC + g * 8);
  const short* iph = Inh + ((size_t)(b * NPIX + n0 + q) * DIMC + g * 8);

  f32x4 acc[4] = {{0,0,0,0},{0,0,0,0},{0,0,0,0},{0,0,0,0}};
#pragma unroll
  for (int c0 = 0; c0 < DIMC; c0 += 32) {
    s16x8 ah = *(const s16x8*)(wph + c0);
#pragma unroll
    for (int st = 0; st < 4; ++st) {
      s16x8 bh_ = *(const s16x8*)(iph + (size_t)st * 16 * DIMC + c0);
      acc[st] = MFMA32(ah, bh_, acc[st]);
    }
  }
#pragma unroll
  for (int st = 0; st < 4; ++st)
#pragma unroll
    for (int r = 0; r < 4; ++r)
      Cl[wave * 16 + g * 4 + r][st * 16 + q] = acc[st][r];
  __syncthreads();

  if (o0 < 256) {
    // Q or K: (C+bias)*scale, hi-only, layout [bh][n][32]
    const int n = tid >> 1, oq = tid & 1;
    const int h = o0 >> 5;
    const float* bp = bias + o0 + oq * 16;
    float v[16];
#pragma unroll
    for (int i = 0; i < 16; ++i) v[i] = (Cl[oq * 16 + i][n] + bp[i]) * scale;
    uint32_t a[16];
#pragma unroll
    for (int i = 0; i < 16; ++i) a[i] = rnau(v[i]);
    union { s16x8 s; uint32_t u[4]; } H0, H1;
#pragma unroll
    for (int j = 0; j < 4; ++j) {
      H0.u[j] = pk2(a[2 * j], a[2 * j + 1]);
      H1.u[j] = pk2(a[8 + 2 * j], a[8 + 2 * j + 1]);
    }
    const size_t off = ((size_t)((b * 8 + h) * NPIX + n0 + n)) * HD + oq * 16;
    *(s16x8*)(d1 + off) = H0.s; *(s16x8*)(d1 + off + 8) = H1.s;
  } else {
    // V hi-only: dst [bh][d][n], n mu-permuted within each 32-tile.
    // Thread covers logical keys L = (nc&16)+i, i=0..15, of tile n0+(nc&32).
    // L<16 -> p = 8*(L>>2)+(L&3); L>=16 -> p = 8*((L-16)>>2)+4+(L&3).
    // For i=4j+r: p = 8j + phase + r, phase = (nc&16)?4:0.
    const int o = tid >> 2, nc = (tid & 3) * 16;
    const int h = (o0 - 256) >> 5;
    const float bv = bias[o0 + o];
    float v[16];
#pragma unroll
    for (int i2 = 0; i2 < 4; ++i2) {
      f32x4 t4 = *(const f32x4*)&Cl[o][nc + i2 * 4];
      v[i2 * 4 + 0] = t4[0] + bv; v[i2 * 4 + 1] = t4[1] + bv;
      v[i2 * 4 + 2] = t4[2] + bv; v[i2 * 4 + 3] = t4[3] + bv;
    }
    uint32_t a[16];
#pragma unroll
    for (int i = 0; i < 16; ++i) a[i] = rnau(v[i]);
    short* po = Vhi + ((size_t)((b * 8 + h) * HD + o)) * NPIX + n0 + (nc & 32);
    const int phase = (nc & 16) ? 4 : 0;
#pragma unroll
    for (int j = 0; j < 4; ++j) {
      uint2 wv;
      wv.x = pk2(a[4 * j], a[4 * j + 1]);
      wv.y = pk2(a[4 * j + 2], a[4 * j + 3]);
      *(uint2*)(po + phase + 8 * j) = wv;
    }
  }
}

// ---------------------------------------------------------------------------
// MFMA flash attention, 4-wave intra-block split-K + XCD swizzle, and now
// IN-REGISTER P: V's mu-permuted layout makes each lane's own
// [exp(SA0[0..3]), exp(SA1[0..3])] the exact PV B-fragment. The per-step
// LDS P round-trip (stores+reads+lgkmcnt+2.1M bank conflicts) is deleted;
// LDS is used only for the final cross-wave O/L reduction.
// ---------------------------------------------------------------------------
__global__ __launch_bounds__(256) void attn_fused(
    const short* __restrict__ Qhi,   // [bh][n][32]
    const short* __restrict__ Khi,   // [bh][n][32]
    const short* __restrict__ Vhi,   // [bh][32][N] (n mu-permuted per 32-tile)
    short* __restrict__ zh) {        // [b][pix][256] scrambled
  const int li = blockIdx.x;         // 0..1151
  const int r144 = li >> 3;          // 0..143
  const int bh = 2 * (li & 7) + (r144 >= 72 ? 1 : 0);
  const int qb = (r144 >= 72) ? r144 - 72 : r144;  // 32-row q block
  const int tid = threadIdx.x;
  const int wave = tid >> 6, lane = tid & 63;
  const int g = lane >> 4, q = lane & 15;
  const int base = qb * 32;

  // LDS: final reduction only. [4 waves][64 lanes][20 f32] = 20480 B.
  __shared__ __align__(16) float R[4][64][20];

  const size_t qoff = ((size_t)bh * NPIX + base + q) * HD + g * 8;
  const s16x8 qhA = *(const s16x8*)(Qhi + qoff);
  const s16x8 qhB = *(const s16x8*)(Qhi + qoff + 16 * HD);

  const short* kp = Khi + ((size_t)bh * NPIX + wave * KPW + q) * HD + g * 8;
  const short* vp = Vhi + ((size_t)bh * HD + q) * NPIX + wave * KPW + g * 8;

  const f32x4 Z4 = {0.f, 0.f, 0.f, 0.f};
  f32x4 OA0 = Z4, OA1 = Z4, OB0 = Z4, OB1 = Z4;
  f32x4 LA = Z4, LB = Z4;
  s16x8 kb[3][2], vb[3][2], pfA, pfB, vp0, vp1;

  union { s16x8 s; uint32_t u[4]; } ONE, ZZ;
  ONE.u[0] = 0x3F803F80u; ONE.u[1] = 0x3F803F80u;
  ONE.u[2] = 0x3F803F80u; ONE.u[3] = 0x3F803F80u;
  ZZ.u[0] = 0; ZZ.u[1] = 0; ZZ.u[2] = 0; ZZ.u[3] = 0;
  const s16x8 ones = ONE.s;
  pfA = ZZ.s; pfB = ZZ.s;          // P=0 -> first O/L MFMAs add exact 0
  vp0 = ones; vp1 = ones;          // finite (avoid NaN*0)

  kb[0][0] = *(const s16x8*)(kp);
  kb[0][1] = *(const s16x8*)(kp + 16 * HD);
  vb[0][0] = *(const s16x8*)(vp);
  vb[0][1] = *(const s16x8*)(vp + 16 * NPIX);
  kb[1][0] = *(const s16x8*)(kp + KT * HD);
  kb[1][1] = *(const s16x8*)(kp + KT * HD + 16 * HD);
  vb[1][0] = *(const s16x8*)(vp + KT);
  vb[1][1] = *(const s16x8*)(vp + KT + 16 * NPIX);

#define ATTN_STEP(CUR, NX2, T)                                                \
  {                                                                           \
    if ((T) + 2 < NTW) {                                                      \
      const short* kpn = kp + ((T) + 2) * (KT * HD);                          \
      const short* vpn = vp + ((T) + 2) * KT;                                 \
      kb[NX2][0] = *(const s16x8*)(kpn);                                      \
      kb[NX2][1] = *(const s16x8*)(kpn + 16 * HD);                            \
      vb[NX2][0] = *(const s16x8*)(vpn);                                      \
      vb[NX2][1] = *(const s16x8*)(vpn + 16 * NPIX);                          \
    }                                                                         \
    f32x4 SA0 = MFMA32(kb[CUR][0], qhA, Z4);                                  \
    f32x4 SA1 = MFMA32(kb[CUR][1], qhA, Z4);                                  \
    f32x4 SB0 = MFMA32(kb[CUR][0], qhB, Z4);                                  \
    f32x4 SB1 = MFMA32(kb[CUR][1], qhB, Z4);                                  \
    OA0 = MFMA32(vp0, pfA, OA0);                                              \
    OA1 = MFMA32(vp1, pfA, OA1);                                              \
    OB0 = MFMA32(vp0, pfB, OB0);                                              \
    OB1 = MFMA32(vp1, pfB, OB1);                                              \
    LA  = MFMA32(ones, pfA, LA);                                              \
    LB  = MFMA32(ones, pfB, LB);                                              \
    {                                                                         \
      f32x4 p0, p1;                                                           \
      p0[0] = exp2f(SA0[0]); p0[1] = exp2f(SA0[1]);                           \
      p0[2] = exp2f(SA0[2]); p0[3] = exp2f(SA0[3]);                           \
      p1[0] = exp2f(SA1[0]); p1[1] = exp2f(SA1[1]);                           \
      p1[2] = exp2f(SA1[2]); p1[3] = exp2f(SA1[3]);                           \
      union { s16x8 s; uint32_t u[4]; } PA;                                   \
      PA.u[0] = pk2(rnau(p0[0]), rnau(p0[1]));                                \
      PA.u[1] = pk2(rnau(p0[2]), rnau(p0[3]));                                \
      PA.u[2] = pk2(rnau(p1[0]), rnau(p1[1]));                                \
      PA.u[3] = pk2(rnau(p1[2]), rnau(p1[3]));                                \
      pfA = PA.s;                                                             \
    }                                                                         \
    {                                                                         \
      f32x4 p0, p1;                                                           \
      p0[0] = exp2f(SB0[0]); p0[1] = exp2f(SB0[1]);                           \
      p0[2] = exp2f(SB0[2]); p0[3] = exp2f(SB0[3]);                           \
      p1[0] = exp2f(SB1[0]); p1[1] = exp2f(SB1[1]);                           \
      p1[2] = exp2f(SB1[2]); p1[3] = exp2f(SB1[3]);                           \
      union { s16x8 s; uint32_t u[4]; } PB;                                   \
      PB.u[0] = pk2(rnau(p0[0]), rnau(p0[1]));                                \
      PB.u[1] = pk2(rnau(p0[2]), rnau(p0[3]));                                \
      PB.u[2] = pk2(rnau(p1[0]), rnau(p1[1]));                                \
      PB.u[3] = pk2(rnau(p1[2]), rnau(p1[3]));                                \
      pfB = PB.s;                                                             \
    }                                                                         \
    vp0 = vb[CUR][0]; vp1 = vb[CUR][1];                                       \
  }

#pragma unroll 1
  for (int tt = 0; tt < NTW; tt += 3) {
    ATTN_STEP(0, 2, tt);
    ATTN_STEP(1, 0, tt + 1);
    ATTN_STEP(2, 1, tt + 2);
  }
#undef ATTN_STEP

  // Tail: consume P of the wave's last tile
  OA0 = MFMA32(vp0, pfA, OA0);
  OA1 = MFMA32(vp1, pfA, OA1);
  OB0 = MFMA32(vp0, pfB, OB0);
  OB1 = MFMA32(vp1, pfB, OB1);
  LA  = MFMA32(ones, pfA, LA);
  LB  = MFMA32(ones, pfB, LB);

  {
    float* rw = &R[wave][lane][0];
    *(f32x4*)&rw[0]  = OA0;   // d = g*4+r        (rows nA)
    *(f32x4*)&rw[4]  = OA1;   // d = 16+g*4+r
    *(f32x4*)&rw[8]  = OB0;   // d = g*4+r        (rows nB)
    *(f32x4*)&rw[12] = OB1;   // d = 16+g*4+r
    rw[16] = LA[0];           // L rows identical -> LA[0] = L[q-row A]
    rw[17] = LB[0];
  }
  __syncthreads();
  {
    // 256 threads: lane-slot l2, element group eg (4 O-elems each).
    const int l2 = tid & 63, eg = tid >> 6;
    const int g2 = l2 >> 4, q2 = l2 & 15;
    f32x4 s = {0.f, 0.f, 0.f, 0.f};
    float Lt = 0.f;
#pragma unroll
    for (int w = 0; w < NWAVE; ++w) {
      const f32x4 pv = *(const f32x4*)&R[w][l2][eg * 4];
      s[0] += pv[0]; s[1] += pv[1]; s[2] += pv[2]; s[3] += pv[3];
      Lt += R[w][l2][16 + (eg >> 1)];
    }
    const float inv = 1.f / Lt;
    const int h = bh & 7, b = bh >> 3;
    const int n = base + ((eg & 2) ? 16 : 0) + q2;
    const int d0 = ((eg & 1) ? 16 : 0) + g2 * 4;
    const int c = n / 9, r = n - c * 9;
    short* zp = zh + ((size_t)(b * NPIX + r * 256 + h * HD + d0)) * DIMC + c;
#pragma unroll
    for (int j = 0; j < 4; ++j)
      zp[(size_t)j * DIMC] = (short)(rnau(s[j] * inv) >> 16);
  }
}

// ---------------------------------------------------------------------------
// PROJ GEMM: single MFMA/tile (Wh*Zh). fp32 out + bias. UNCHANGED.
// ---------------------------------------------------------------------------
__global__ __launch_bounds__(128) void gemm_proj_hi(
    const short* __restrict__ Wh,
    const float* __restrict__ bias,
    const short* __restrict__ Zh,
    float* __restrict__ out) {
  __shared__ __align__(16) float Cl[32][68];
  const int n0 = blockIdx.x * 64;
  const int o0 = blockIdx.y * 32;
  const int b  = blockIdx.z;
  const int tid = threadIdx.x;
  const int wave = tid >> 6, lane = tid & 63;
  const int g = lane >> 4, q = lane & 15;

  const short* wph = Wh + ((o0 + wave * 16 + q) * DIMC + g * 8);
  const short* iph = Zh + ((size_t)(b * NPIX + n0 + q) * DIMC + g * 8);

  f32x4 acc[4] = {{0,0,0,0},{0,0,0,0},{0,0,0,0},{0,0,0,0}};
#pragma unroll
  for (int c0 = 0; c0 < DIMC; c0 += 32) {
    s16x8 ah = *(const s16x8*)(wph + c0);
#pragma unroll
    for (int st = 0; st < 4; ++st) {
      s16x8 bh_ = *(const s16x8*)(iph + (size_t)st * 16 * DIMC + c0);
      acc[st] = MFMA32(ah, bh_, acc[st]);
    }
  }
#pragma unroll
  for (int st = 0; st < 4; ++st)
#pragma unroll
    for (int r = 0; r < 4; ++r)
      Cl[wave * 16 + g * 4 + r][st * 16 + q] = acc[st][r];
  __syncthreads();

  const int o = tid >> 2, nc = (tid & 3) * 16;
  const float bv = bias[o0 + o];
  float* op = out + ((size_t)b * DIMC + o0 + o) * NPIX + n0 + nc;
#pragma unroll
  for (int i2 = 0; i2 < 4; ++i2) {
    f32x4 v = *(const f32x4*)&Cl[o][nc + i2 * 4];
    v[0] += bv; v[1] += bv; v[2] += bv; v[3] += bv;
    *(f32x4*)(op + i2 * 4) = v;
  }
}

// ---------------------------------------------------------------------------
extern "C" void kernel_launch(void* const* d_in, const int* in_sizes, int n_in,
                              void* d_out, int out_size, void* d_ws, size_t ws_size,
                              hipStream_t stream) {
  const float* x      = (const float*)d_in[0];
  const float* q_w    = (const float*)d_in[1];
  const float* q_b    = (const float*)d_in[2];
  const float* kv_w   = (const float*)d_in[3];
  const float* kv_b   = (const float*)d_in[4];
  const float* proj_w = (const float*)d_in[5];
  const float* proj_b = (const float*)d_in[6];
  float* out = (float*)d_out;

  // Workspace (offsets preserved).
  char* w = (char*)d_ws;
  float* xavg = (float*)w;                       // 4,718,592
  short* Xh   = (short*)(w + 4718592);
  short* Ah   = (short*)(w + 9437184);
  short* Wth  = (short*)(w + 28311552);          // 524,288 (hi only)
  short* Qhi  = (short*)(w + 29360128);          // 2,359,296
  short* Khi  = (short*)(w + 31719424);
  short* Vhi  = (short*)(w + 34078720);
  short* Zh   = (short*)(w + 37322752);          // 2,359,296

  const float qscale = 0.17677669529663689f * 1.4426950408889634f; // d^-0.5*log2(e)

  pool_kernel<<<BATCH * DIMC, 256, 0, stream>>>(x, xavg);
  conv_all<<<704, 256, 0, stream>>>(x, xavg, q_w, kv_w, proj_w, Xh, Ah, Wth);
  gemm_qkv_hi<<<dim3(36, 24, 2), 128, 0, stream>>>(Wth, q_b, kv_b,
                                                   Xh, Ah, Qhi, Khi, Vhi, qscale);
  attn_fused<<<1152, 256, 0, stream>>>(Qhi, Khi, Vhi, Zh);
  gemm_proj_hi<<<dim3(36, 8, 2), 128, 0, stream>>>(Wth + 196608, proj_b, Zh, out);
}